// Round 5
// baseline (520.476 us; speedup 1.0000x reference)
//
#include <hip/hip_runtime.h>
#include <cstdint>
#include <cstddef>

#define NNODES 100000
#define NEDGES 1000000
#define NREL 3
#define RN (NREL * NNODES)
#define EPB 2048                       // elements per scan block (256 thr x 8)
#define SCAN_BLOCKS ((RN + EPB - 1) / EPB)   // 147

// ---------------- CSR build ----------------

__global__ __launch_bounds__(256) void hist_kernel(
    const int* __restrict__ srcv, const int* __restrict__ ety, int* __restrict__ cnt)
{
    const int e = (int)(blockIdx.x * 256 + threadIdx.x);
    if (e < NEDGES) atomicAdd(&cnt[ety[e] * NNODES + srcv[e]], 1);
}

__global__ __launch_bounds__(256) void scan_reduce(
    const int* __restrict__ cnt, int* __restrict__ bsum)
{
    __shared__ int sd[256];
    const int t = (int)threadIdx.x;
    const int base = (int)blockIdx.x * EPB + t * 8;
    int s = 0;
    #pragma unroll
    for (int i = 0; i < 8; ++i)
        if (base + i < RN) s += cnt[base + i];
    sd[t] = s;
    __syncthreads();
    for (int st = 128; st > 0; st >>= 1) {
        if (t < st) sd[t] += sd[t + st];
        __syncthreads();
    }
    if (t == 0) bsum[blockIdx.x] = sd[0];
}

__global__ __launch_bounds__(256) void scan_blocksums(int* __restrict__ bsum, int nb)
{
    __shared__ int buf0[256], buf1[256];
    const int t = (int)threadIdx.x;
    buf0[t] = (t < nb) ? bsum[t] : 0;
    __syncthreads();
    int* a = buf0; int* b = buf1;
    for (int st = 1; st < 256; st <<= 1) {
        int v = a[t];
        if (t >= st) v += a[t - st];
        b[t] = v;
        __syncthreads();
        int* tmp = a; a = b; b = tmp;
    }
    if (t < nb) bsum[t] = (t == 0) ? 0 : a[t - 1];   // exclusive
}

__global__ __launch_bounds__(256) void scan_final(
    const int* __restrict__ cnt, const int* __restrict__ bsum,
    int* __restrict__ off, int* __restrict__ wptr)
{
    __shared__ int buf0[256], buf1[256];
    const int t = (int)threadIdx.x;
    const int base = (int)blockIdx.x * EPB + t * 8;
    int v[8];
    int tot = 0;
    #pragma unroll
    for (int i = 0; i < 8; ++i) {
        v[i] = (base + i < RN) ? cnt[base + i] : 0;
        tot += v[i];
    }
    buf0[t] = tot;
    __syncthreads();
    int* a = buf0; int* b = buf1;
    for (int st = 1; st < 256; st <<= 1) {
        int s = a[t];
        if (t >= st) s += a[t - st];
        b[t] = s;
        __syncthreads();
        int* tmp = a; a = b; b = tmp;
    }
    int o = bsum[blockIdx.x] + ((t == 0) ? 0 : a[t - 1]);
    #pragma unroll
    for (int i = 0; i < 8; ++i) {
        if (base + i < RN) { off[base + i] = o; wptr[base + i] = o; }
        o += v[i];
    }
    if (blockIdx.x == 0 && t == 0) off[RN] = NEDGES;
}

__global__ __launch_bounds__(256) void fill_kernel(
    const int* __restrict__ srcv, const int* __restrict__ dstv,
    const int* __restrict__ ety, int* __restrict__ wptr, int* __restrict__ ebuf)
{
    const int e = (int)(blockIdx.x * 256 + threadIdx.x);
    if (e < NEDGES) {
        const int pos = atomicAdd(&wptr[ety[e] * NNODES + srcv[e]], 1);
        ebuf[pos] = dstv[e];
    }
}

// ---------------- fused gather + dense ----------------
// out = relu( Agg @ W1^T + h @ (W2a+W2b)^T + biases ), Agg[n] = sum h[dst] over
// CSR bucket (rel, n). Block = 64 nodes x 64 outs, 256 threads, 4x4 acc/thread.
// Gather phase: wave wv sums rows for nodes [wv*16, wv*16+16) into LDS Agg,
// two independent node streams per wave for load-level parallelism.
// Agg row stride PAD keeps writes 2-way (free) and float4 k-reads 16B-aligned.
template<int K>
__global__ __launch_bounds__(256) void fused_layer(
    const int* __restrict__ off, const int* __restrict__ ebuf,
    const float* __restrict__ h,                         // [N,K], gather source AND dense A2
    const float* __restrict__ W1, const float* __restrict__ W2a, const float* __restrict__ W2b,
    const float* __restrict__ B1, const float* __restrict__ B2, const float* __restrict__ B3,
    float* __restrict__ out, int rel, int nNodes)
{
    constexpr int PAD = (K == 128) ? 132 : 68;   // stride%8==4 -> bank-spread, 16B-aligned rows
    __shared__ float Agg[64][PAD];
    __shared__ float As[16][64];
    __shared__ float Ws[16][64];

    const int t    = (int)threadIdx.x;
    const int lane = t & 63;
    const int wv   = t >> 6;            // wave 0..3
    const int n0   = (int)blockIdx.x * 64;

    // ---- gather phase ----
    const int* o = off + rel * NNODES;
    #pragma unroll 1
    for (int ii = 0; ii < 8; ++ii) {
        const int nlA = wv * 16 + ii;
        const int nlB = nlA + 8;
        const int nA = n0 + nlA, nB = n0 + nlB;
        int jA = 0, eA = 0, jB = 0, eB = 0;
        if (nA < nNodes) { jA = o[nA]; eA = o[nA + 1]; }
        if (nB < nNodes) { jB = o[nB]; eB = o[nB + 1]; }
        float a0A = 0.f, a1A = 0.f, a0B = 0.f, a1B = 0.f;
        while (jA < eA && jB < eB) {     // two independent load chains in flight
            const int dA = ebuf[jA++];
            const int dB = ebuf[jB++];
            const float* hA = h + (size_t)dA * K;
            const float* hB = h + (size_t)dB * K;
            a0A += hA[lane]; a0B += hB[lane];
            if (K == 128) { a1A += hA[64 + lane]; a1B += hB[64 + lane]; }
        }
        while (jA < eA) {
            const float* hA = h + (size_t)ebuf[jA++] * K;
            a0A += hA[lane];
            if (K == 128) a1A += hA[64 + lane];
        }
        while (jB < eB) {
            const float* hB = h + (size_t)ebuf[jB++] * K;
            a0B += hB[lane];
            if (K == 128) a1B += hB[64 + lane];
        }
        Agg[nlA][lane] = a0A;
        Agg[nlB][lane] = a0B;
        if (K == 128) { Agg[nlA][64 + lane] = a1A; Agg[nlB][64 + lane] = a1B; }
    }
    __syncthreads();

    // ---- dense phase ----
    const int tx = t & 15;        // output-group (4 outs)
    const int ty = t >> 4;        // node-group (4 nodes)
    const int srow = t >> 2;      // staging row (node or out), 0..63
    const int skk  = (t & 3) * 4; // staging k offset within 16-chunk

    float4 acc[4];
    #pragma unroll
    for (int i = 0; i < 4; ++i) acc[i] = make_float4(0.f, 0.f, 0.f, 0.f);

    const int KC = K / 16;
    const int nA = n0 + srow;

    // C1: A from LDS Agg, W1 staged chunk-wise
    #pragma unroll 1
    for (int c = 0; c < KC; ++c) {
        const float4 wv4 = *(const float4*)(W1 + (size_t)srow * K + c * 16 + skk);
        __syncthreads();              // prior chunk's Ws reads done
        Ws[skk + 0][srow] = wv4.x; Ws[skk + 1][srow] = wv4.y;
        Ws[skk + 2][srow] = wv4.z; Ws[skk + 3][srow] = wv4.w;
        __syncthreads();
        #pragma unroll
        for (int k4 = 0; k4 < 4; ++k4) {
            const float4 w0 = *(const float4*)&Ws[k4 * 4 + 0][tx * 4];
            const float4 w1 = *(const float4*)&Ws[k4 * 4 + 1][tx * 4];
            const float4 w2 = *(const float4*)&Ws[k4 * 4 + 2][tx * 4];
            const float4 w3 = *(const float4*)&Ws[k4 * 4 + 3][tx * 4];
            #pragma unroll
            for (int i = 0; i < 4; ++i) {
                const float4 a4 = *(const float4*)&Agg[ty * 4 + i][c * 16 + k4 * 4];
                acc[i].x = fmaf(a4.x, w0.x, acc[i].x); acc[i].y = fmaf(a4.x, w0.y, acc[i].y);
                acc[i].z = fmaf(a4.x, w0.z, acc[i].z); acc[i].w = fmaf(a4.x, w0.w, acc[i].w);
                acc[i].x = fmaf(a4.y, w1.x, acc[i].x); acc[i].y = fmaf(a4.y, w1.y, acc[i].y);
                acc[i].z = fmaf(a4.y, w1.z, acc[i].z); acc[i].w = fmaf(a4.y, w1.w, acc[i].w);
                acc[i].x = fmaf(a4.z, w2.x, acc[i].x); acc[i].y = fmaf(a4.z, w2.y, acc[i].y);
                acc[i].z = fmaf(a4.z, w2.z, acc[i].z); acc[i].w = fmaf(a4.z, w2.w, acc[i].w);
                acc[i].x = fmaf(a4.w, w3.x, acc[i].x); acc[i].y = fmaf(a4.w, w3.y, acc[i].y);
                acc[i].z = fmaf(a4.w, w3.z, acc[i].z); acc[i].w = fmaf(a4.w, w3.w, acc[i].w);
            }
        }
    }

    // C2: A2 = h from global (staged), W = W2a+W2b staged
    #pragma unroll 1
    for (int c = 0; c < KC; ++c) {
        const int k0 = c * 16;
        float4 av = make_float4(0.f, 0.f, 0.f, 0.f);
        if (nA < nNodes) av = *(const float4*)(h + (size_t)nA * K + k0 + skk);
        const float4 a = *(const float4*)(W2a + (size_t)srow * K + k0 + skk);
        const float4 b = *(const float4*)(W2b + (size_t)srow * K + k0 + skk);
        const float4 wv4 = make_float4(a.x + b.x, a.y + b.y, a.z + b.z, a.w + b.w);

        __syncthreads();
        As[skk + 0][srow] = av.x; As[skk + 1][srow] = av.y;
        As[skk + 2][srow] = av.z; As[skk + 3][srow] = av.w;
        Ws[skk + 0][srow] = wv4.x; Ws[skk + 1][srow] = wv4.y;
        Ws[skk + 2][srow] = wv4.z; Ws[skk + 3][srow] = wv4.w;
        __syncthreads();

        #pragma unroll
        for (int k = 0; k < 16; ++k) {
            const float4 a4 = *(const float4*)&As[k][ty * 4];
            const float4 w4 = *(const float4*)&Ws[k][tx * 4];
            acc[0].x = fmaf(a4.x, w4.x, acc[0].x); acc[0].y = fmaf(a4.x, w4.y, acc[0].y);
            acc[0].z = fmaf(a4.x, w4.z, acc[0].z); acc[0].w = fmaf(a4.x, w4.w, acc[0].w);
            acc[1].x = fmaf(a4.y, w4.x, acc[1].x); acc[1].y = fmaf(a4.y, w4.y, acc[1].y);
            acc[1].z = fmaf(a4.y, w4.z, acc[1].z); acc[1].w = fmaf(a4.y, w4.w, acc[1].w);
            acc[2].x = fmaf(a4.z, w4.x, acc[2].x); acc[2].y = fmaf(a4.z, w4.y, acc[2].y);
            acc[2].z = fmaf(a4.z, w4.z, acc[2].z); acc[2].w = fmaf(a4.z, w4.w, acc[2].w);
            acc[3].x = fmaf(a4.w, w4.x, acc[3].x); acc[3].y = fmaf(a4.w, w4.y, acc[3].y);
            acc[3].z = fmaf(a4.w, w4.z, acc[3].z); acc[3].w = fmaf(a4.w, w4.w, acc[3].w);
        }
    }

    // ---- epilogue ----
    const float4 b1 = *(const float4*)(B1 + tx * 4);
    const float4 b2 = *(const float4*)(B2 + tx * 4);
    const float4 b3 = *(const float4*)(B3 + tx * 4);
    const float4 bias = make_float4(b1.x + b2.x + b3.x, b1.y + b2.y + b3.y,
                                    b1.z + b2.z + b3.z, b1.w + b2.w + b3.w);
    #pragma unroll
    for (int i = 0; i < 4; ++i) {
        const int n = n0 + ty * 4 + i;
        if (n < nNodes) {
            float4 r = make_float4(acc[i].x + bias.x, acc[i].y + bias.y,
                                   acc[i].z + bias.z, acc[i].w + bias.w);
            r.x = r.x > 0.f ? r.x : 0.f;
            r.y = r.y > 0.f ? r.y : 0.f;
            r.z = r.z > 0.f ? r.z : 0.f;
            r.w = r.w > 0.f ? r.w : 0.f;
            *(float4*)(out + (size_t)n * 64 + tx * 4) = r;
        }
    }
}

extern "C" void kernel_launch(void* const* d_in, const int* in_sizes, int n_in,
                              void* d_out, int out_size, void* d_ws, size_t ws_size,
                              hipStream_t stream)
{
    const float* x    = (const float*)d_in[0];
    const int*   eidx = (const int*)d_in[1];
    const int*   ety  = (const int*)d_in[2];
    const int*   srcv = eidx;            // edge_index[0]
    const int*   dstv = eidx + NEDGES;   // edge_index[1]

    const float* wl0 = (const float*)d_in[3];
    const float* bl0 = (const float*)d_in[4];
    const float* w00 = (const float*)d_in[5];
    const float* b00 = (const float*)d_in[6];
    const float* w10 = (const float*)d_in[7];
    const float* b10 = (const float*)d_in[8];

    const float* wl1 = (const float*)d_in[9];
    const float* bl1 = (const float*)d_in[10];
    const float* w01 = (const float*)d_in[11];
    const float* b01 = (const float*)d_in[12];
    const float* w11 = (const float*)d_in[13];
    const float* b11 = (const float*)d_in[14];

    const float* wl2 = (const float*)d_in[15];
    const float* bl2 = (const float*)d_in[16];
    const float* w02 = (const float*)d_in[17];
    const float* b02 = (const float*)d_in[18];
    const float* w12 = (const float*)d_in[19];
    const float* b12 = (const float*)d_in[20];

    // ---- workspace layout (~34 MB of d_ws) ----
    char* p = (char*)d_ws;
    auto alloc = [&](size_t bytes) {
        char* r = p;
        p += (bytes + 255) & ~(size_t)255;
        return r;
    };
    int* cnt  = (int*)alloc((size_t)RN * 4);
    int* off  = (int*)alloc((size_t)(RN + 1) * 4);
    int* wptr = (int*)alloc((size_t)RN * 4);
    int* bsum = (int*)alloc(1024);
    int* ebuf = (int*)alloc((size_t)NEDGES * 4);
    float* h2 = (float*)alloc((size_t)NNODES * 64 * sizeof(float));   // 25.6 MB
    float* h1 = (float*)d_out;                                        // reuse d_out as h1

    const int edgeGrid  = (NEDGES + 255) / 256;
    const int fusedGrid = (NNODES + 63) / 64;

    // ---- CSR build (once; serves all 3 relations) ----
    hipMemsetAsync(cnt, 0, (size_t)RN * 4, stream);
    hist_kernel<<<edgeGrid, 256, 0, stream>>>(srcv, ety, cnt);
    scan_reduce<<<SCAN_BLOCKS, 256, 0, stream>>>(cnt, bsum);
    scan_blocksums<<<1, 256, 0, stream>>>(bsum, SCAN_BLOCKS);
    scan_final<<<SCAN_BLOCKS, 256, 0, stream>>>(cnt, bsum, off, wptr);
    fill_kernel<<<edgeGrid, 256, 0, stream>>>(srcv, dstv, ety, wptr, ebuf);

    // ---- Layer 0: K = 128 (h = x = x_in) ----
    fused_layer<128><<<fusedGrid, 256, 0, stream>>>(off, ebuf, x, wl0, w00, w10,
                                                    bl0, b00, b10, h1, 0, NNODES);
    // ---- Layer 1: K = 64 ----
    fused_layer<64><<<fusedGrid, 256, 0, stream>>>(off, ebuf, h1, wl1, w01, w11,
                                                   bl1, b01, b11, h2, 1, NNODES);
    // ---- Layer 2: K = 64 (final output) ----
    fused_layer<64><<<fusedGrid, 256, 0, stream>>>(off, ebuf, h2, wl2, w02, w12,
                                                   bl2, b02, b12, (float*)d_out, 2, NNODES);
}

// Round 6
// 503.550 us; speedup vs baseline: 1.0336x; 1.0336x over previous
//
#include <hip/hip_runtime.h>
#include <cstdint>
#include <cstddef>

#define NNODES 100000
#define NEDGES 1000000
#define NREL 3
#define RN (NREL * NNODES)
#define EPB 2048                       // elements per scan block (256 thr x 8)
#define SCAN_BLOCKS ((RN + EPB - 1) / EPB)   // 147

// ---- bf16 pack/unpack (bit ops; RTN) ----
__device__ __forceinline__ uint32_t pack_bf2(float a, float b) {
    uint32_t ua = __float_as_uint(a), ub = __float_as_uint(b);
    ua = (ua + 0x7fffu + ((ua >> 16) & 1u)) >> 16;
    ub = (ub + 0x7fffu + ((ub >> 16) & 1u)) >> 16;
    return ua | (ub << 16);
}
__device__ __forceinline__ float bf_lo(uint32_t u) { return __uint_as_float(u << 16); }
__device__ __forceinline__ float bf_hi(uint32_t u) { return __uint_as_float(u & 0xffff0000u); }

// ---------------- CSR build ----------------

__global__ __launch_bounds__(256) void hist_kernel(
    const int* __restrict__ srcv, const int* __restrict__ ety, int* __restrict__ cnt)
{
    const int e = (int)(blockIdx.x * 256 + threadIdx.x);
    if (e < NEDGES) atomicAdd(&cnt[ety[e] * NNODES + srcv[e]], 1);
}

__global__ __launch_bounds__(256) void scan_reduce(
    const int* __restrict__ cnt, int* __restrict__ bsum)
{
    __shared__ int sd[256];
    const int t = (int)threadIdx.x;
    const int base = (int)blockIdx.x * EPB + t * 8;
    int s = 0;
    #pragma unroll
    for (int i = 0; i < 8; ++i)
        if (base + i < RN) s += cnt[base + i];
    sd[t] = s;
    __syncthreads();
    for (int st = 128; st > 0; st >>= 1) {
        if (t < st) sd[t] += sd[t + st];
        __syncthreads();
    }
    if (t == 0) bsum[blockIdx.x] = sd[0];
}

__global__ __launch_bounds__(256) void scan_blocksums(int* __restrict__ bsum, int nb)
{
    __shared__ int buf0[256], buf1[256];
    const int t = (int)threadIdx.x;
    buf0[t] = (t < nb) ? bsum[t] : 0;
    __syncthreads();
    int* a = buf0; int* b = buf1;
    for (int st = 1; st < 256; st <<= 1) {
        int v = a[t];
        if (t >= st) v += a[t - st];
        b[t] = v;
        __syncthreads();
        int* tmp = a; a = b; b = tmp;
    }
    if (t < nb) bsum[t] = (t == 0) ? 0 : a[t - 1];   // exclusive
}

__global__ __launch_bounds__(256) void scan_final(
    const int* __restrict__ cnt, const int* __restrict__ bsum,
    int* __restrict__ off, int* __restrict__ wptr)
{
    __shared__ int buf0[256], buf1[256];
    const int t = (int)threadIdx.x;
    const int base = (int)blockIdx.x * EPB + t * 8;
    int v[8];
    int tot = 0;
    #pragma unroll
    for (int i = 0; i < 8; ++i) {
        v[i] = (base + i < RN) ? cnt[base + i] : 0;
        tot += v[i];
    }
    buf0[t] = tot;
    __syncthreads();
    int* a = buf0; int* b = buf1;
    for (int st = 1; st < 256; st <<= 1) {
        int s = a[t];
        if (t >= st) s += a[t - st];
        b[t] = s;
        __syncthreads();
        int* tmp = a; a = b; b = tmp;
    }
    int o = bsum[blockIdx.x] + ((t == 0) ? 0 : a[t - 1]);
    #pragma unroll
    for (int i = 0; i < 8; ++i) {
        if (base + i < RN) { off[base + i] = o; wptr[base + i] = o; }
        o += v[i];
    }
    if (blockIdx.x == 0 && t == 0) off[RN] = NEDGES;
}

__global__ __launch_bounds__(256) void fill_kernel(
    const int* __restrict__ srcv, const int* __restrict__ dstv,
    const int* __restrict__ ety, int* __restrict__ wptr, int* __restrict__ ebuf)
{
    const int e = (int)(blockIdx.x * 256 + threadIdx.x);
    if (e < NEDGES) {
        const int pos = atomicAdd(&wptr[ety[e] * NNODES + srcv[e]], 1);
        ebuf[pos] = dstv[e];
    }
}

// ---------------- gemm_y: y = A @ W^T, bf16 output ----------------
// A [N,K] fp32, W [64,K] fp32, y [N,32] uint32 (2 bf16 chans each).
template<int K>
__global__ __launch_bounds__(256) void gemm_y(
    const float* __restrict__ A, const float* __restrict__ W,
    uint32_t* __restrict__ y, int nNodes)
{
    __shared__ float As[16][64];
    __shared__ float Ws[16][64];

    const int t  = (int)threadIdx.x;
    const int tx = t & 15, ty = t >> 4;
    const int n0 = (int)blockIdx.x * 64;
    const int srow = t >> 2, skk = (t & 3) * 4;
    const int nA = n0 + srow;

    float4 acc[4];
    #pragma unroll
    for (int i = 0; i < 4; ++i) acc[i] = make_float4(0.f, 0.f, 0.f, 0.f);

    #pragma unroll 1
    for (int c = 0; c < K / 16; ++c) {
        const int k0 = c * 16;
        float4 av = make_float4(0.f, 0.f, 0.f, 0.f);
        if (nA < nNodes) av = *(const float4*)(A + (size_t)nA * K + k0 + skk);
        const float4 wv4 = *(const float4*)(W + (size_t)srow * K + k0 + skk);

        __syncthreads();
        As[skk + 0][srow] = av.x; As[skk + 1][srow] = av.y;
        As[skk + 2][srow] = av.z; As[skk + 3][srow] = av.w;
        Ws[skk + 0][srow] = wv4.x; Ws[skk + 1][srow] = wv4.y;
        Ws[skk + 2][srow] = wv4.z; Ws[skk + 3][srow] = wv4.w;
        __syncthreads();

        #pragma unroll
        for (int k = 0; k < 16; ++k) {
            const float4 a4 = *(const float4*)&As[k][ty * 4];
            const float4 w4 = *(const float4*)&Ws[k][tx * 4];
            acc[0].x = fmaf(a4.x, w4.x, acc[0].x); acc[0].y = fmaf(a4.x, w4.y, acc[0].y);
            acc[0].z = fmaf(a4.x, w4.z, acc[0].z); acc[0].w = fmaf(a4.x, w4.w, acc[0].w);
            acc[1].x = fmaf(a4.y, w4.x, acc[1].x); acc[1].y = fmaf(a4.y, w4.y, acc[1].y);
            acc[1].z = fmaf(a4.y, w4.z, acc[1].z); acc[1].w = fmaf(a4.y, w4.w, acc[1].w);
            acc[2].x = fmaf(a4.z, w4.x, acc[2].x); acc[2].y = fmaf(a4.z, w4.y, acc[2].y);
            acc[2].z = fmaf(a4.z, w4.z, acc[2].z); acc[2].w = fmaf(a4.z, w4.w, acc[2].w);
            acc[3].x = fmaf(a4.w, w4.x, acc[3].x); acc[3].y = fmaf(a4.w, w4.y, acc[3].y);
            acc[3].z = fmaf(a4.w, w4.z, acc[3].z); acc[3].w = fmaf(a4.w, w4.w, acc[3].w);
        }
    }

    #pragma unroll
    for (int i = 0; i < 4; ++i) {
        const int n = n0 + ty * 4 + i;
        if (n < nNodes) {
            uint2 p;
            p.x = pack_bf2(acc[i].x, acc[i].y);
            p.y = pack_bf2(acc[i].z, acc[i].w);
            *(uint2*)(y + (size_t)n * 32 + tx * 2) = p;
        }
    }
}

// ---------------- dense layer with fused y-space gather + next-y ----------------
// out = relu( gather_sum(ybuf over bucket(rel,n)) + h @ (W2a+W2b)^T + B1+B2+B3 )
// if HASY: ynext = out @ Wy^T (bf16), via LDS Ot pass.
template<int K, bool HASY>
__global__ __launch_bounds__(256) void dense_layer(
    const float* __restrict__ h,              // [N,K]
    const uint32_t* __restrict__ ybuf,        // [N,32] bf16x2 gather source
    const int* __restrict__ off, const int* __restrict__ ebuf, int rel,
    const float* __restrict__ W2a, const float* __restrict__ W2b,   // [64,K]
    const float* __restrict__ B1, const float* __restrict__ B2, const float* __restrict__ B3,
    const float* __restrict__ Wy,             // [64,64] next-layer wl (HASY)
    float* __restrict__ out,                  // [N,64]
    uint32_t* __restrict__ ynext,             // [N,32] (HASY)
    int nNodes)
{
    __shared__ float As[16][64];
    __shared__ float Ws[16][64];
    __shared__ float Ot[HASY ? 64 : 1][76];   // stride 76: 2-way writes, conflict-free reads

    const int t  = (int)threadIdx.x;
    const int tx = t & 15, ty = t >> 4;
    const int n0 = (int)blockIdx.x * 64;
    const int srow = t >> 2, skk = (t & 3) * 4;
    const int nA = n0 + srow;

    float4 acc[4];
    #pragma unroll
    for (int i = 0; i < 4; ++i) acc[i] = make_float4(0.f, 0.f, 0.f, 0.f);

    // ---- main loop: h @ (W2a+W2b)^T ----
    #pragma unroll 1
    for (int c = 0; c < K / 16; ++c) {
        const int k0 = c * 16;
        float4 av = make_float4(0.f, 0.f, 0.f, 0.f);
        if (nA < nNodes) av = *(const float4*)(h + (size_t)nA * K + k0 + skk);
        const float4 a = *(const float4*)(W2a + (size_t)srow * K + k0 + skk);
        const float4 b = *(const float4*)(W2b + (size_t)srow * K + k0 + skk);
        const float4 wv4 = make_float4(a.x + b.x, a.y + b.y, a.z + b.z, a.w + b.w);

        __syncthreads();
        As[skk + 0][srow] = av.x; As[skk + 1][srow] = av.y;
        As[skk + 2][srow] = av.z; As[skk + 3][srow] = av.w;
        Ws[skk + 0][srow] = wv4.x; Ws[skk + 1][srow] = wv4.y;
        Ws[skk + 2][srow] = wv4.z; Ws[skk + 3][srow] = wv4.w;
        __syncthreads();

        #pragma unroll
        for (int k = 0; k < 16; ++k) {
            const float4 a4 = *(const float4*)&As[k][ty * 4];
            const float4 w4 = *(const float4*)&Ws[k][tx * 4];
            acc[0].x = fmaf(a4.x, w4.x, acc[0].x); acc[0].y = fmaf(a4.x, w4.y, acc[0].y);
            acc[0].z = fmaf(a4.x, w4.z, acc[0].z); acc[0].w = fmaf(a4.x, w4.w, acc[0].w);
            acc[1].x = fmaf(a4.y, w4.x, acc[1].x); acc[1].y = fmaf(a4.y, w4.y, acc[1].y);
            acc[1].z = fmaf(a4.y, w4.z, acc[1].z); acc[1].w = fmaf(a4.y, w4.w, acc[1].w);
            acc[2].x = fmaf(a4.z, w4.x, acc[2].x); acc[2].y = fmaf(a4.z, w4.y, acc[2].y);
            acc[2].z = fmaf(a4.z, w4.z, acc[2].z); acc[2].w = fmaf(a4.z, w4.w, acc[2].w);
            acc[3].x = fmaf(a4.w, w4.x, acc[3].x); acc[3].y = fmaf(a4.w, w4.y, acc[3].y);
            acc[3].z = fmaf(a4.w, w4.z, acc[3].z); acc[3].w = fmaf(a4.w, w4.w, acc[3].w);
        }
    }

    // ---- epilogue: bias + y-space gather + relu ----
    const float4 b1 = *(const float4*)(B1 + tx * 4);
    const float4 b2 = *(const float4*)(B2 + tx * 4);
    const float4 b3 = *(const float4*)(B3 + tx * 4);
    const float4 bias = make_float4(b1.x + b2.x + b3.x, b1.y + b2.y + b3.y,
                                    b1.z + b2.z + b3.z, b1.w + b2.w + b3.w);
    const int* o = off + rel * NNODES;

    #pragma unroll 1
    for (int i = 0; i < 4; ++i) {
        const int n = n0 + ty * 4 + i;
        float4 r = make_float4(acc[i].x + bias.x, acc[i].y + bias.y,
                               acc[i].z + bias.z, acc[i].w + bias.w);
        if (n < nNodes) {
            int j = o[n];
            const int e1 = o[n + 1];
            float4 g = make_float4(0.f, 0.f, 0.f, 0.f);
            for (; j < e1; ++j) {
                const uint2 v = *(const uint2*)(ybuf + (size_t)ebuf[j] * 32 + tx * 2);
                g.x += bf_lo(v.x); g.y += bf_hi(v.x);
                g.z += bf_lo(v.y); g.w += bf_hi(v.y);
            }
            r.x += g.x; r.y += g.y; r.z += g.z; r.w += g.w;
        }
        r.x = r.x > 0.f ? r.x : 0.f;
        r.y = r.y > 0.f ? r.y : 0.f;
        r.z = r.z > 0.f ? r.z : 0.f;
        r.w = r.w > 0.f ? r.w : 0.f;
        if (n < nNodes) *(float4*)(out + (size_t)n * 64 + tx * 4) = r;
        if constexpr (HASY) *(float4*)&Ot[ty * 4 + i][tx * 4] = r;
    }

    // ---- next-layer y: ynext = Ot @ Wy^T (bf16) ----
    if constexpr (HASY) {
        float4 ya[4];
        #pragma unroll
        for (int i = 0; i < 4; ++i) ya[i] = make_float4(0.f, 0.f, 0.f, 0.f);

        #pragma unroll 1
        for (int c = 0; c < 4; ++c) {
            const float4 wv4 = *(const float4*)(Wy + (size_t)srow * 64 + c * 16 + skk);
            __syncthreads();          // prior Ws reads + (c==0) Ot writes complete
            Ws[skk + 0][srow] = wv4.x; Ws[skk + 1][srow] = wv4.y;
            Ws[skk + 2][srow] = wv4.z; Ws[skk + 3][srow] = wv4.w;
            __syncthreads();
            #pragma unroll
            for (int k4 = 0; k4 < 4; ++k4) {
                const float4 w0 = *(const float4*)&Ws[k4 * 4 + 0][tx * 4];
                const float4 w1 = *(const float4*)&Ws[k4 * 4 + 1][tx * 4];
                const float4 w2 = *(const float4*)&Ws[k4 * 4 + 2][tx * 4];
                const float4 w3 = *(const float4*)&Ws[k4 * 4 + 3][tx * 4];
                #pragma unroll
                for (int i = 0; i < 4; ++i) {
                    const float4 a4 = *(const float4*)&Ot[ty * 4 + i][c * 16 + k4 * 4];
                    ya[i].x = fmaf(a4.x, w0.x, ya[i].x); ya[i].y = fmaf(a4.x, w0.y, ya[i].y);
                    ya[i].z = fmaf(a4.x, w0.z, ya[i].z); ya[i].w = fmaf(a4.x, w0.w, ya[i].w);
                    ya[i].x = fmaf(a4.y, w1.x, ya[i].x); ya[i].y = fmaf(a4.y, w1.y, ya[i].y);
                    ya[i].z = fmaf(a4.y, w1.z, ya[i].z); ya[i].w = fmaf(a4.y, w1.w, ya[i].w);
                    ya[i].x = fmaf(a4.z, w2.x, ya[i].x); ya[i].y = fmaf(a4.z, w2.y, ya[i].y);
                    ya[i].z = fmaf(a4.z, w2.z, ya[i].z); ya[i].w = fmaf(a4.z, w2.w, ya[i].w);
                    ya[i].x = fmaf(a4.w, w3.x, ya[i].x); ya[i].y = fmaf(a4.w, w3.y, ya[i].y);
                    ya[i].z = fmaf(a4.w, w3.z, ya[i].z); ya[i].w = fmaf(a4.w, w3.w, ya[i].w);
                }
            }
        }
        #pragma unroll
        for (int i = 0; i < 4; ++i) {
            const int n = n0 + ty * 4 + i;
            if (n < nNodes) {
                uint2 p;
                p.x = pack_bf2(ya[i].x, ya[i].y);
                p.y = pack_bf2(ya[i].z, ya[i].w);
                *(uint2*)(ynext + (size_t)n * 32 + tx * 2) = p;
            }
        }
    }
}

extern "C" void kernel_launch(void* const* d_in, const int* in_sizes, int n_in,
                              void* d_out, int out_size, void* d_ws, size_t ws_size,
                              hipStream_t stream)
{
    const float* x    = (const float*)d_in[0];
    const int*   eidx = (const int*)d_in[1];
    const int*   ety  = (const int*)d_in[2];
    const int*   srcv = eidx;            // edge_index[0]
    const int*   dstv = eidx + NEDGES;   // edge_index[1]

    const float* wl0 = (const float*)d_in[3];
    const float* bl0 = (const float*)d_in[4];
    const float* w00 = (const float*)d_in[5];
    const float* b00 = (const float*)d_in[6];
    const float* w10 = (const float*)d_in[7];
    const float* b10 = (const float*)d_in[8];

    const float* wl1 = (const float*)d_in[9];
    const float* bl1 = (const float*)d_in[10];
    const float* w01 = (const float*)d_in[11];
    const float* b01 = (const float*)d_in[12];
    const float* w11 = (const float*)d_in[13];
    const float* b11 = (const float*)d_in[14];

    const float* wl2 = (const float*)d_in[15];
    const float* bl2 = (const float*)d_in[16];
    const float* w02 = (const float*)d_in[17];
    const float* b02 = (const float*)d_in[18];
    const float* w12 = (const float*)d_in[19];
    const float* b12 = (const float*)d_in[20];

    // ---- workspace layout (~59 MB; 76.8 MB proven-safe) ----
    char* p = (char*)d_ws;
    auto alloc = [&](size_t bytes) {
        char* r = p;
        p += (bytes + 255) & ~(size_t)255;
        return r;
    };
    int* cnt  = (int*)alloc((size_t)RN * 4);
    int* off  = (int*)alloc((size_t)(RN + 1) * 4);
    int* wptr = (int*)alloc((size_t)RN * 4);
    int* bsum = (int*)alloc(1024);
    int* ebuf = (int*)alloc((size_t)NEDGES * 4);
    uint32_t* yA = (uint32_t*)alloc((size_t)NNODES * 32 * 4);          // 12.8 MB
    uint32_t* yB = (uint32_t*)alloc((size_t)NNODES * 32 * 4);          // 12.8 MB
    float* h2    = (float*)alloc((size_t)NNODES * 64 * sizeof(float)); // 25.6 MB
    float* h1    = (float*)d_out;                                      // reuse d_out as h1

    const int edgeGrid  = (NEDGES + 255) / 256;
    const int tileGrid  = (NNODES + 63) / 64;

    // ---- CSR build (once; serves all 3 relations) ----
    hipMemsetAsync(cnt, 0, (size_t)RN * 4, stream);
    hist_kernel<<<edgeGrid, 256, 0, stream>>>(srcv, ety, cnt);
    scan_reduce<<<SCAN_BLOCKS, 256, 0, stream>>>(cnt, bsum);
    scan_blocksums<<<1, 256, 0, stream>>>(bsum, SCAN_BLOCKS);
    scan_final<<<SCAN_BLOCKS, 256, 0, stream>>>(cnt, bsum, off, wptr);
    fill_kernel<<<edgeGrid, 256, 0, stream>>>(srcv, dstv, ety, wptr, ebuf);

    // ---- y0 = x @ wl0^T ----
    gemm_y<128><<<tileGrid, 256, 0, stream>>>(x, wl0, yA, NNODES);

    // ---- Layer 0: h1 = relu(gather(y0) + x@(w00+w10)^T + b), y1 = h1@wl1^T ----
    dense_layer<128, true><<<tileGrid, 256, 0, stream>>>(
        x, yA, off, ebuf, 0, w00, w10, bl0, b00, b10, wl1, h1, yB, NNODES);

    // ---- Layer 1: h2 = relu(gather(y1) + h1@(w01+w11)^T + b), y2 = h2@wl2^T ----
    dense_layer<64, true><<<tileGrid, 256, 0, stream>>>(
        h1, yB, off, ebuf, 1, w01, w11, bl1, b01, b11, wl2, h2, yA, NNODES);

    // ---- Layer 2: out = relu(gather(y2) + h2@(w02+w12)^T + b) ----
    dense_layer<64, false><<<tileGrid, 256, 0, stream>>>(
        h2, yA, off, ebuf, 2, w02, w12, bl2, b02, b12, nullptr,
        (float*)d_out, nullptr, NNODES);
}

// Round 7
// 421.880 us; speedup vs baseline: 1.2337x; 1.1936x over previous
//
#include <hip/hip_runtime.h>
#include <cstdint>
#include <cstddef>

#define NNODES 100000
#define NEDGES 1000000
#define NREL 3
#define RN (NREL * NNODES)
#define EPB 2048                       // elements per scan block (256 thr x 8)
#define SCAN_BLOCKS ((RN + EPB - 1) / EPB)   // 147

// ---- bf16 pack/unpack (bit ops; RTN) ----
__device__ __forceinline__ uint32_t pack_bf2(float a, float b) {
    uint32_t ua = __float_as_uint(a), ub = __float_as_uint(b);
    ua = (ua + 0x7fffu + ((ua >> 16) & 1u)) >> 16;
    ub = (ub + 0x7fffu + ((ub >> 16) & 1u)) >> 16;
    return ua | (ub << 16);
}
__device__ __forceinline__ float bf_lo(uint32_t u) { return __uint_as_float(u << 16); }
__device__ __forceinline__ float bf_hi(uint32_t u) { return __uint_as_float(u & 0xffff0000u); }

// ---------------- CSR build ----------------

__global__ __launch_bounds__(256) void hist_kernel(
    const int* __restrict__ srcv, const int* __restrict__ ety, int* __restrict__ cnt)
{
    const int e = (int)(blockIdx.x * 256 + threadIdx.x);
    if (e < NEDGES) atomicAdd(&cnt[ety[e] * NNODES + srcv[e]], 1);
}

__global__ __launch_bounds__(256) void scan_reduce(
    const int* __restrict__ cnt, int* __restrict__ bsum)
{
    __shared__ int sd[256];
    const int t = (int)threadIdx.x;
    const int base = (int)blockIdx.x * EPB + t * 8;
    int s = 0;
    #pragma unroll
    for (int i = 0; i < 8; ++i)
        if (base + i < RN) s += cnt[base + i];
    sd[t] = s;
    __syncthreads();
    for (int st = 128; st > 0; st >>= 1) {
        if (t < st) sd[t] += sd[t + st];
        __syncthreads();
    }
    if (t == 0) bsum[blockIdx.x] = sd[0];
}

__global__ __launch_bounds__(256) void scan_blocksums(int* __restrict__ bsum, int nb)
{
    __shared__ int buf0[256], buf1[256];
    const int t = (int)threadIdx.x;
    buf0[t] = (t < nb) ? bsum[t] : 0;
    __syncthreads();
    int* a = buf0; int* b = buf1;
    for (int st = 1; st < 256; st <<= 1) {
        int v = a[t];
        if (t >= st) v += a[t - st];
        b[t] = v;
        __syncthreads();
        int* tmp = a; a = b; b = tmp;
    }
    if (t < nb) bsum[t] = (t == 0) ? 0 : a[t - 1];   // exclusive
}

__global__ __launch_bounds__(256) void scan_final(
    const int* __restrict__ cnt, const int* __restrict__ bsum,
    int* __restrict__ off, int* __restrict__ wptr)
{
    __shared__ int buf0[256], buf1[256];
    const int t = (int)threadIdx.x;
    const int base = (int)blockIdx.x * EPB + t * 8;
    int v[8];
    int tot = 0;
    #pragma unroll
    for (int i = 0; i < 8; ++i) {
        v[i] = (base + i < RN) ? cnt[base + i] : 0;
        tot += v[i];
    }
    buf0[t] = tot;
    __syncthreads();
    int* a = buf0; int* b = buf1;
    for (int st = 1; st < 256; st <<= 1) {
        int s = a[t];
        if (t >= st) s += a[t - st];
        b[t] = s;
        __syncthreads();
        int* tmp = a; a = b; b = tmp;
    }
    int o = bsum[blockIdx.x] + ((t == 0) ? 0 : a[t - 1]);
    #pragma unroll
    for (int i = 0; i < 8; ++i) {
        if (base + i < RN) { off[base + i] = o; wptr[base + i] = o; }
        o += v[i];
    }
    if (blockIdx.x == 0 && t == 0) off[RN] = NEDGES;
}

__global__ __launch_bounds__(256) void fill_kernel(
    const int* __restrict__ srcv, const int* __restrict__ dstv,
    const int* __restrict__ ety, int* __restrict__ wptr, int* __restrict__ ebuf)
{
    const int e = (int)(blockIdx.x * 256 + threadIdx.x);
    if (e < NEDGES) {
        const int pos = atomicAdd(&wptr[ety[e] * NNODES + srcv[e]], 1);
        ebuf[pos] = dstv[e];
    }
}

// ---------------- gemm_y: y = A @ W^T, bf16 output ----------------
template<int K>
__global__ __launch_bounds__(256) void gemm_y(
    const float* __restrict__ A, const float* __restrict__ W,
    uint32_t* __restrict__ y, int nNodes)
{
    __shared__ float As[16][64];
    __shared__ float Ws[16][64];

    const int t  = (int)threadIdx.x;
    const int tx = t & 15, ty = t >> 4;
    const int n0 = (int)blockIdx.x * 64;
    const int srow = t >> 2, skk = (t & 3) * 4;
    const int nA = n0 + srow;

    float4 acc[4];
    #pragma unroll
    for (int i = 0; i < 4; ++i) acc[i] = make_float4(0.f, 0.f, 0.f, 0.f);

    #pragma unroll 1
    for (int c = 0; c < K / 16; ++c) {
        const int k0 = c * 16;
        float4 av = make_float4(0.f, 0.f, 0.f, 0.f);
        if (nA < nNodes) av = *(const float4*)(A + (size_t)nA * K + k0 + skk);
        const float4 wv4 = *(const float4*)(W + (size_t)srow * K + k0 + skk);

        __syncthreads();
        As[skk + 0][srow] = av.x; As[skk + 1][srow] = av.y;
        As[skk + 2][srow] = av.z; As[skk + 3][srow] = av.w;
        Ws[skk + 0][srow] = wv4.x; Ws[skk + 1][srow] = wv4.y;
        Ws[skk + 2][srow] = wv4.z; Ws[skk + 3][srow] = wv4.w;
        __syncthreads();

        #pragma unroll
        for (int k = 0; k < 16; ++k) {
            const float4 a4 = *(const float4*)&As[k][ty * 4];
            const float4 w4 = *(const float4*)&Ws[k][tx * 4];
            acc[0].x = fmaf(a4.x, w4.x, acc[0].x); acc[0].y = fmaf(a4.x, w4.y, acc[0].y);
            acc[0].z = fmaf(a4.x, w4.z, acc[0].z); acc[0].w = fmaf(a4.x, w4.w, acc[0].w);
            acc[1].x = fmaf(a4.y, w4.x, acc[1].x); acc[1].y = fmaf(a4.y, w4.y, acc[1].y);
            acc[1].z = fmaf(a4.y, w4.z, acc[1].z); acc[1].w = fmaf(a4.y, w4.w, acc[1].w);
            acc[2].x = fmaf(a4.z, w4.x, acc[2].x); acc[2].y = fmaf(a4.z, w4.y, acc[2].y);
            acc[2].z = fmaf(a4.z, w4.z, acc[2].z); acc[2].w = fmaf(a4.z, w4.w, acc[2].w);
            acc[3].x = fmaf(a4.w, w4.x, acc[3].x); acc[3].y = fmaf(a4.w, w4.y, acc[3].y);
            acc[3].z = fmaf(a4.w, w4.z, acc[3].z); acc[3].w = fmaf(a4.w, w4.w, acc[3].w);
        }
    }

    #pragma unroll
    for (int i = 0; i < 4; ++i) {
        const int n = n0 + ty * 4 + i;
        if (n < nNodes) {
            uint2 p;
            p.x = pack_bf2(acc[i].x, acc[i].y);
            p.y = pack_bf2(acc[i].z, acc[i].w);
            *(uint2*)(y + (size_t)n * 32 + tx * 2) = p;
        }
    }
}

// ---------------- dense layer with fused y-space gather + next-y ----------------
// out = relu( gather_sum(ybuf over bucket(rel,n)) + h @ (W2a+W2b)^T + B1+B2+B3 )
// Gather: bucket ranges loaded at kernel ENTRY (hidden under GEMM); the 4
// node-buckets per thread are walked in LOCKSTEP (4 independent load chains).
// if HASY: ynext = out @ Wy^T via bf16-packed LDS Ot (9 KB, stride 36 uints).
template<int K, bool HASY>
__global__ __launch_bounds__(256) void dense_layer(
    const float* __restrict__ h,              // [N,K]
    const uint32_t* __restrict__ ybuf,        // [N,32] bf16x2 gather source
    const int* __restrict__ off, const int* __restrict__ ebuf, int rel,
    const float* __restrict__ W2a, const float* __restrict__ W2b,   // [64,K]
    const float* __restrict__ B1, const float* __restrict__ B2, const float* __restrict__ B3,
    const float* __restrict__ Wy,             // [64,64] next-layer wl (HASY)
    float* __restrict__ out,                  // [N,64]
    uint32_t* __restrict__ ynext,             // [N,32] (HASY)
    int nNodes)
{
    __shared__ float As[16][64];
    __shared__ float Ws[16][64];
    __shared__ uint32_t Ot[HASY ? 64 : 1][36];   // bf16x2; stride 36: 2-way writes

    const int t  = (int)threadIdx.x;
    const int tx = t & 15, ty = t >> 4;
    const int n0 = (int)blockIdx.x * 64;
    const int srow = t >> 2, skk = (t & 3) * 4;
    const int nA = n0 + srow;

    // ---- early bucket-range loads (latency hidden under main GEMM) ----
    const int* o = off + rel * NNODES;
    int jj[4], ee[4];
    #pragma unroll
    for (int i = 0; i < 4; ++i) {
        const int n = n0 + ty * 4 + i;
        if (n < nNodes) { jj[i] = o[n]; ee[i] = o[n + 1]; }
        else            { jj[i] = 0;    ee[i] = 0; }
    }

    float4 acc[4];
    #pragma unroll
    for (int i = 0; i < 4; ++i) acc[i] = make_float4(0.f, 0.f, 0.f, 0.f);

    // ---- main loop: h @ (W2a+W2b)^T ----
    #pragma unroll 1
    for (int c = 0; c < K / 16; ++c) {
        const int k0 = c * 16;
        float4 av = make_float4(0.f, 0.f, 0.f, 0.f);
        if (nA < nNodes) av = *(const float4*)(h + (size_t)nA * K + k0 + skk);
        const float4 a = *(const float4*)(W2a + (size_t)srow * K + k0 + skk);
        const float4 b = *(const float4*)(W2b + (size_t)srow * K + k0 + skk);
        const float4 wv4 = make_float4(a.x + b.x, a.y + b.y, a.z + b.z, a.w + b.w);

        __syncthreads();
        As[skk + 0][srow] = av.x; As[skk + 1][srow] = av.y;
        As[skk + 2][srow] = av.z; As[skk + 3][srow] = av.w;
        Ws[skk + 0][srow] = wv4.x; Ws[skk + 1][srow] = wv4.y;
        Ws[skk + 2][srow] = wv4.z; Ws[skk + 3][srow] = wv4.w;
        __syncthreads();

        #pragma unroll
        for (int k = 0; k < 16; ++k) {
            const float4 a4 = *(const float4*)&As[k][ty * 4];
            const float4 w4 = *(const float4*)&Ws[k][tx * 4];
            acc[0].x = fmaf(a4.x, w4.x, acc[0].x); acc[0].y = fmaf(a4.x, w4.y, acc[0].y);
            acc[0].z = fmaf(a4.x, w4.z, acc[0].z); acc[0].w = fmaf(a4.x, w4.w, acc[0].w);
            acc[1].x = fmaf(a4.y, w4.x, acc[1].x); acc[1].y = fmaf(a4.y, w4.y, acc[1].y);
            acc[1].z = fmaf(a4.y, w4.z, acc[1].z); acc[1].w = fmaf(a4.y, w4.w, acc[1].w);
            acc[2].x = fmaf(a4.z, w4.x, acc[2].x); acc[2].y = fmaf(a4.z, w4.y, acc[2].y);
            acc[2].z = fmaf(a4.z, w4.z, acc[2].z); acc[2].w = fmaf(a4.z, w4.w, acc[2].w);
            acc[3].x = fmaf(a4.w, w4.x, acc[3].x); acc[3].y = fmaf(a4.w, w4.y, acc[3].y);
            acc[3].z = fmaf(a4.w, w4.z, acc[3].z); acc[3].w = fmaf(a4.w, w4.w, acc[3].w);
        }
    }

    // ---- lockstep 4-chain gather (4 independent load chains in flight) ----
    float4 g[4];
    #pragma unroll
    for (int i = 0; i < 4; ++i) g[i] = make_float4(0.f, 0.f, 0.f, 0.f);

    for (;;) {
        int d[4];
        bool any = false;
        #pragma unroll
        for (int i = 0; i < 4; ++i) {
            d[i] = -1;
            if (jj[i] < ee[i]) { d[i] = ebuf[jj[i]]; any = true; }
        }
        if (!any) break;
        uint2 v[4];
        #pragma unroll
        for (int i = 0; i < 4; ++i) {
            v[i] = make_uint2(0u, 0u);
            if (d[i] >= 0) v[i] = *(const uint2*)(ybuf + (size_t)d[i] * 32 + tx * 2);
        }
        #pragma unroll
        for (int i = 0; i < 4; ++i) {
            if (d[i] >= 0) {
                g[i].x += bf_lo(v[i].x); g[i].y += bf_hi(v[i].x);
                g[i].z += bf_lo(v[i].y); g[i].w += bf_hi(v[i].y);
                jj[i]++;
            }
        }
    }

    // ---- epilogue: bias + gather + relu; store out + Ot ----
    const float4 b1 = *(const float4*)(B1 + tx * 4);
    const float4 b2 = *(const float4*)(B2 + tx * 4);
    const float4 b3 = *(const float4*)(B3 + tx * 4);
    const float4 bias = make_float4(b1.x + b2.x + b3.x, b1.y + b2.y + b3.y,
                                    b1.z + b2.z + b3.z, b1.w + b2.w + b3.w);
    #pragma unroll
    for (int i = 0; i < 4; ++i) {
        const int n = n0 + ty * 4 + i;
        float4 r = make_float4(acc[i].x + bias.x + g[i].x, acc[i].y + bias.y + g[i].y,
                               acc[i].z + bias.z + g[i].z, acc[i].w + bias.w + g[i].w);
        r.x = r.x > 0.f ? r.x : 0.f;
        r.y = r.y > 0.f ? r.y : 0.f;
        r.z = r.z > 0.f ? r.z : 0.f;
        r.w = r.w > 0.f ? r.w : 0.f;
        if (n < nNodes) *(float4*)(out + (size_t)n * 64 + tx * 4) = r;
        if constexpr (HASY) {
            uint2 p;
            p.x = pack_bf2(r.x, r.y);
            p.y = pack_bf2(r.z, r.w);
            *(uint2*)&Ot[ty * 4 + i][tx * 2] = p;
        }
    }

    // ---- next-layer y: ynext = Ot @ Wy^T (bf16 in, bf16 out) ----
    if constexpr (HASY) {
        float4 ya[4];
        #pragma unroll
        for (int i = 0; i < 4; ++i) ya[i] = make_float4(0.f, 0.f, 0.f, 0.f);

        #pragma unroll 1
        for (int c = 0; c < 4; ++c) {
            const float4 wv4 = *(const float4*)(Wy + (size_t)srow * 64 + c * 16 + skk);
            __syncthreads();          // prior Ws reads + Ot writes complete
            Ws[skk + 0][srow] = wv4.x; Ws[skk + 1][srow] = wv4.y;
            Ws[skk + 2][srow] = wv4.z; Ws[skk + 3][srow] = wv4.w;
            __syncthreads();
            #pragma unroll
            for (int k4 = 0; k4 < 4; ++k4) {
                const float4 w0 = *(const float4*)&Ws[k4 * 4 + 0][tx * 4];
                const float4 w1 = *(const float4*)&Ws[k4 * 4 + 1][tx * 4];
                const float4 w2 = *(const float4*)&Ws[k4 * 4 + 2][tx * 4];
                const float4 w3 = *(const float4*)&Ws[k4 * 4 + 3][tx * 4];
                #pragma unroll
                for (int i = 0; i < 4; ++i) {
                    const uint2 u = *(const uint2*)&Ot[ty * 4 + i][c * 8 + k4 * 2];
                    const float4 a4 = make_float4(bf_lo(u.x), bf_hi(u.x), bf_lo(u.y), bf_hi(u.y));
                    ya[i].x = fmaf(a4.x, w0.x, ya[i].x); ya[i].y = fmaf(a4.x, w0.y, ya[i].y);
                    ya[i].z = fmaf(a4.x, w0.z, ya[i].z); ya[i].w = fmaf(a4.x, w0.w, ya[i].w);
                    ya[i].x = fmaf(a4.y, w1.x, ya[i].x); ya[i].y = fmaf(a4.y, w1.y, ya[i].y);
                    ya[i].z = fmaf(a4.y, w1.z, ya[i].z); ya[i].w = fmaf(a4.y, w1.w, ya[i].w);
                    ya[i].x = fmaf(a4.z, w2.x, ya[i].x); ya[i].y = fmaf(a4.z, w2.y, ya[i].y);
                    ya[i].z = fmaf(a4.z, w2.z, ya[i].z); ya[i].w = fmaf(a4.z, w2.w, ya[i].w);
                    ya[i].x = fmaf(a4.w, w3.x, ya[i].x); ya[i].y = fmaf(a4.w, w3.y, ya[i].y);
                    ya[i].z = fmaf(a4.w, w3.z, ya[i].z); ya[i].w = fmaf(a4.w, w3.w, ya[i].w);
                }
            }
        }
        #pragma unroll
        for (int i = 0; i < 4; ++i) {
            const int n = n0 + ty * 4 + i;
            if (n < nNodes) {
                uint2 p;
                p.x = pack_bf2(ya[i].x, ya[i].y);
                p.y = pack_bf2(ya[i].z, ya[i].w);
                *(uint2*)(ynext + (size_t)n * 32 + tx * 2) = p;
            }
        }
    }
}

extern "C" void kernel_launch(void* const* d_in, const int* in_sizes, int n_in,
                              void* d_out, int out_size, void* d_ws, size_t ws_size,
                              hipStream_t stream)
{
    const float* x    = (const float*)d_in[0];
    const int*   eidx = (const int*)d_in[1];
    const int*   ety  = (const int*)d_in[2];
    const int*   srcv = eidx;            // edge_index[0]
    const int*   dstv = eidx + NEDGES;   // edge_index[1]

    const float* wl0 = (const float*)d_in[3];
    const float* bl0 = (const float*)d_in[4];
    const float* w00 = (const float*)d_in[5];
    const float* b00 = (const float*)d_in[6];
    const float* w10 = (const float*)d_in[7];
    const float* b10 = (const float*)d_in[8];

    const float* wl1 = (const float*)d_in[9];
    const float* bl1 = (const float*)d_in[10];
    const float* w01 = (const float*)d_in[11];
    const float* b01 = (const float*)d_in[12];
    const float* w11 = (const float*)d_in[13];
    const float* b11 = (const float*)d_in[14];

    const float* wl2 = (const float*)d_in[15];
    const float* bl2 = (const float*)d_in[16];
    const float* w02 = (const float*)d_in[17];
    const float* b02 = (const float*)d_in[18];
    const float* w12 = (const float*)d_in[19];
    const float* b12 = (const float*)d_in[20];

    // ---- workspace layout (~59 MB; 76.8 MB proven-safe) ----
    char* p = (char*)d_ws;
    auto alloc = [&](size_t bytes) {
        char* r = p;
        p += (bytes + 255) & ~(size_t)255;
        return r;
    };
    int* cnt  = (int*)alloc((size_t)RN * 4);
    int* off  = (int*)alloc((size_t)(RN + 1) * 4);
    int* wptr = (int*)alloc((size_t)RN * 4);
    int* bsum = (int*)alloc(1024);
    int* ebuf = (int*)alloc((size_t)NEDGES * 4);
    uint32_t* yA = (uint32_t*)alloc((size_t)NNODES * 32 * 4);          // 12.8 MB
    uint32_t* yB = (uint32_t*)alloc((size_t)NNODES * 32 * 4);          // 12.8 MB
    float* h2    = (float*)alloc((size_t)NNODES * 64 * sizeof(float)); // 25.6 MB
    float* h1    = (float*)d_out;                                      // reuse d_out as h1

    const int edgeGrid  = (NEDGES + 255) / 256;
    const int tileGrid  = (NNODES + 63) / 64;

    // ---- CSR build (once; serves all 3 relations) ----
    hipMemsetAsync(cnt, 0, (size_t)RN * 4, stream);
    hist_kernel<<<edgeGrid, 256, 0, stream>>>(srcv, ety, cnt);
    scan_reduce<<<SCAN_BLOCKS, 256, 0, stream>>>(cnt, bsum);
    scan_blocksums<<<1, 256, 0, stream>>>(bsum, SCAN_BLOCKS);
    scan_final<<<SCAN_BLOCKS, 256, 0, stream>>>(cnt, bsum, off, wptr);
    fill_kernel<<<edgeGrid, 256, 0, stream>>>(srcv, dstv, ety, wptr, ebuf);

    // ---- y0 = x @ wl0^T ----
    gemm_y<128><<<tileGrid, 256, 0, stream>>>(x, wl0, yA, NNODES);

    // ---- Layer 0: h1 = relu(gather(y0) + x@(w00+w10)^T + b), y1 = h1@wl1^T ----
    dense_layer<128, true><<<tileGrid, 256, 0, stream>>>(
        x, yA, off, ebuf, 0, w00, w10, bl0, b00, b10, wl1, h1, yB, NNODES);

    // ---- Layer 1: h2 = relu(gather(y1) + h1@(w01+w11)^T + b), y2 = h2@wl2^T ----
    dense_layer<64, true><<<tileGrid, 256, 0, stream>>>(
        h1, yB, off, ebuf, 1, w01, w11, bl1, b01, b11, wl2, h2, yA, NNODES);

    // ---- Layer 2: out = relu(gather(y2) + h2@(w02+w12)^T + b) ----
    dense_layer<64, false><<<tileGrid, 256, 0, stream>>>(
        h2, yA, off, ebuf, 2, w02, w12, bl2, b02, b12, nullptr,
        (float*)d_out, nullptr, NNODES);
}